// Round 1
// baseline (1406.103 us; speedup 1.0000x reference)
//
#include <hip/hip_runtime.h>
#include <cstdint>
#include <cstddef>

typedef int v4i __attribute__((ext_vector_type(4)));
typedef int v16i __attribute__((ext_vector_type(16)));

#define BK 128  // bytes of K per LDS tile (i8)

// ---------------- async global->LDS, 16B per lane ----------------
__device__ __forceinline__ void gld_lds16(const void* g, void* l) {
  __builtin_amdgcn_global_load_lds(
      (const __attribute__((address_space(1))) unsigned int*)g,
      (__attribute__((address_space(3))) unsigned int*)l, 16, 0, 0);
}

// Stage NI*64 rows x 128 B into LDS with XOR chunk swizzle (512 threads).
// LDS chunk (r, cs) holds global chunk cg = cs ^ (r&7): 8 consecutive rows'
// same-logical-chunk b128 reads hit 8 distinct bank quads (verified layout).
// global_load_lds contract: wave-uniform LDS base + lane*16 (linear dest),
// per-lane global source carries the swizzle.
template <int NI>
__device__ __forceinline__ void stage_rows512(const int8_t* __restrict__ g0, int K,
                                              int kt, int8_t* lds, int tid) {
#pragma unroll
  for (int issue = 0; issue < NI; ++issue) {
    const int f = issue * 512 + tid;
    const int r = f >> 3;
    const int cg = (f & 7) ^ (r & 7);
    gld_lds16(g0 + (size_t)r * K + kt + cg * 16, lds + (f & ~63) * 16);
  }
}

// Read one 32x32x32 i8 MFMA operand fragment (16 B) from a swizzled tile.
// Operand layout (verified): row = lane&31, k-chunk = kk*2 + (lane>>5).
__device__ __forceinline__ v4i read_frag(const int8_t* lds, int row0, int kk, int lane) {
  const int r = row0 + (lane & 31);
  const int cs = (kk * 2 + (lane >> 5)) ^ (r & 7);
  return *(const v4i*)(lds + r * BK + cs * 16);
}

// XCD-contiguous tile remap: HW round-robins consecutive blockIdx across the
// 8 XCDs, so give XCD k a contiguous chunk of tiles (bijective iff nwg%8==0).
__device__ __forceinline__ void xcd_tile(int& bx, int& by) {
  const int gx = gridDim.x;
  const int nwg = gx * gridDim.y;
  int t = blockIdx.x + blockIdx.y * gx;
  if ((nwg & 7) == 0) t = (t & 7) * (nwg >> 3) + (t >> 3);
  bx = t % gx;
  by = t / gx;
}

// ---------------- per-row symmetric int8 quantization (single HBM pass) ----
// s = max(max|row|/127, 1e-8); q = clamp(rint(x/s), -128, 127)  (matches jnp
// bitwise: true division, rint = round-half-even). Row slice cached in regs.
template <int MAXIT>
__global__ __launch_bounds__(256) void quant_rows(const float* __restrict__ X, int C,
                                                  int8_t* __restrict__ Q,
                                                  float* __restrict__ S) {
  const int row = blockIdx.x;
  const float* x = X + (size_t)row * C;
  const int tid = threadIdx.x;
  float4 buf[MAXIT];
  float mx = 0.f;
#pragma unroll
  for (int it = 0; it < MAXIT; ++it) {
    int i = tid * 4 + it * 1024;
    if (i < C) {
      const float4 v = *(const float4*)(x + i);
      buf[it] = v;
      mx = fmaxf(mx, fmaxf(fmaxf(fabsf(v.x), fabsf(v.y)), fmaxf(fabsf(v.z), fabsf(v.w))));
    }
  }
#pragma unroll
  for (int off = 32; off; off >>= 1) mx = fmaxf(mx, __shfl_xor(mx, off));
  __shared__ float wmx[4];
  if ((tid & 63) == 0) wmx[tid >> 6] = mx;
  __syncthreads();
  mx = fmaxf(fmaxf(wmx[0], wmx[1]), fmaxf(wmx[2], wmx[3]));
  const float s = fmaxf(mx / 127.0f, 1e-8f);
  if (tid == 0) S[row] = s;
  int8_t* q = Q + (size_t)row * C;
#pragma unroll
  for (int it = 0; it < MAXIT; ++it) {
    int i = tid * 4 + it * 1024;
    if (i < C) {
      const float4 v = buf[it];
      int q0 = (int)fminf(fmaxf(rintf(v.x / s), -128.f), 127.f);
      int q1 = (int)fminf(fmaxf(rintf(v.y / s), -128.f), 127.f);
      int q2 = (int)fminf(fmaxf(rintf(v.z / s), -128.f), 127.f);
      int q3 = (int)fminf(fmaxf(rintf(v.w / s), -128.f), 127.f);
      *(int*)(q + i) = (q0 & 255) | ((q1 & 255) << 8) | ((q2 & 255) << 16) | ((q3 & 255) << 24);
    }
  }
}

// ---------------- fused gate+up int8 GEMM, SwiGLU epilogue -> h fp32 --------
// 256x128 tile, 8 waves (4M x 2N), wave-tile 64x64 for each of g and u.
// Deep-pipelined schedule (T3+T4+T5): dbuf LDS, full-tile prefetch issued at
// phase 0 (4-phase latency cover), per-kk barrier pair + setprio, single
// vmcnt(0) drain per K-tile (loads stay in flight across the other barriers).
__global__ __launch_bounds__(512, 2) void gemm_gateup(
    const int8_t* __restrict__ Xq, const float* __restrict__ sx,
    const int8_t* __restrict__ Wg, const float* __restrict__ sg,
    const int8_t* __restrict__ Wu, const float* __restrict__ su,
    float* __restrict__ H, int M, int N, int K) {
  __shared__ __align__(16) int8_t lsA[2][256 * BK];
  __shared__ __align__(16) int8_t lsG[2][128 * BK];
  __shared__ __align__(16) int8_t lsU[2][128 * BK];
  const int tid = threadIdx.x;
  const int lane = tid & 63;
  const int wave = tid >> 6;
  const int wr = wave >> 1, wc = wave & 1;
  int bx, by;
  xcd_tile(bx, by);
  const size_t rowA = (size_t)bx * 256;
  const size_t rowB = (size_t)by * 128;
  const int8_t* gA = Xq + rowA * K;
  const int8_t* gG = Wg + rowB * K;
  const int8_t* gU = Wu + rowB * K;

  v16i accg[2][2], accu[2][2];
#pragma unroll
  for (int a = 0; a < 2; ++a)
#pragma unroll
    for (int b = 0; b < 2; ++b)
#pragma unroll
      for (int r = 0; r < 16; ++r) { accg[a][b][r] = 0; accu[a][b][r] = 0; }

  const int nt = K / BK;
  // prologue: tile 0 into buffer 0, full drain once
  stage_rows512<4>(gA, K, 0, lsA[0], tid);
  stage_rows512<2>(gG, K, 0, lsG[0], tid);
  stage_rows512<2>(gU, K, 0, lsU[0], tid);
  asm volatile("s_waitcnt vmcnt(0)" ::: "memory");
  __builtin_amdgcn_s_barrier();

  for (int t = 0; t < nt; ++t) {
    const int p = t & 1;
    if (t + 1 < nt) {  // issue next tile's 8 loads now; waited at kk==3
      const int kt = (t + 1) * BK;
      stage_rows512<4>(gA, K, kt, lsA[p ^ 1], tid);
      stage_rows512<2>(gG, K, kt, lsG[p ^ 1], tid);
      stage_rows512<2>(gU, K, kt, lsU[p ^ 1], tid);
    }
#pragma unroll
    for (int kk = 0; kk < 4; ++kk) {
      v4i a0 = read_frag(lsA[p], wr * 64, kk, lane);
      v4i a1 = read_frag(lsA[p], wr * 64 + 32, kk, lane);
      v4i bg0 = read_frag(lsG[p], wc * 64, kk, lane);
      v4i bu0 = read_frag(lsU[p], wc * 64, kk, lane);
      v4i bg1 = read_frag(lsG[p], wc * 64 + 32, kk, lane);
      v4i bu1 = read_frag(lsU[p], wc * 64 + 32, kk, lane);
      __builtin_amdgcn_s_barrier();
      __builtin_amdgcn_s_setprio(1);
      accg[0][0] = __builtin_amdgcn_mfma_i32_32x32x32_i8(a0, bg0, accg[0][0], 0, 0, 0);
      accg[1][0] = __builtin_amdgcn_mfma_i32_32x32x32_i8(a1, bg0, accg[1][0], 0, 0, 0);
      accu[0][0] = __builtin_amdgcn_mfma_i32_32x32x32_i8(a0, bu0, accu[0][0], 0, 0, 0);
      accu[1][0] = __builtin_amdgcn_mfma_i32_32x32x32_i8(a1, bu0, accu[1][0], 0, 0, 0);
      accg[0][1] = __builtin_amdgcn_mfma_i32_32x32x32_i8(a0, bg1, accg[0][1], 0, 0, 0);
      accg[1][1] = __builtin_amdgcn_mfma_i32_32x32x32_i8(a1, bg1, accg[1][1], 0, 0, 0);
      accu[0][1] = __builtin_amdgcn_mfma_i32_32x32x32_i8(a0, bu1, accu[0][1], 0, 0, 0);
      accu[1][1] = __builtin_amdgcn_mfma_i32_32x32x32_i8(a1, bu1, accu[1][1], 0, 0, 0);
      __builtin_amdgcn_s_setprio(0);
      if (kk == 3) asm volatile("s_waitcnt vmcnt(0)" ::: "memory");
      __builtin_amdgcn_s_barrier();
    }
  }

#pragma unroll
  for (int mi = 0; mi < 2; ++mi)
#pragma unroll
    for (int ni = 0; ni < 2; ++ni) {
#pragma unroll
      for (int r = 0; r < 16; ++r) {
        int rl = wr * 64 + mi * 32 + (r & 3) + 8 * (r >> 2) + 4 * (lane >> 5);
        int cl = wc * 64 + ni * 32 + (lane & 31);
        size_t m = rowA + rl, n = rowB + cl;
        float sxm = sx[m];
        float g = (float)accg[mi][ni][r] * sxm * sg[n];
        float u = (float)accu[mi][ni][r] * sxm * su[n];
        float hv = g / (1.0f + __expf(-g)) * u;  // silu(g)*u
        H[m * (size_t)N + n] = hv;
      }
    }
}

// ---------------- int8 GEMM, scale epilogue -> fp32 out ---------------------
// 256x256 tile, 8 waves (4M x 2N), wave-tile 64x128. Same pipeline schedule.
__global__ __launch_bounds__(512, 2) void gemm_down(
    const int8_t* __restrict__ Aq, const float* __restrict__ sa,
    const int8_t* __restrict__ Bq, const float* __restrict__ sb,
    float* __restrict__ C, int M, int N, int K) {
  __shared__ __align__(16) int8_t lsA[2][256 * BK];
  __shared__ __align__(16) int8_t lsB[2][256 * BK];
  const int tid = threadIdx.x;
  const int lane = tid & 63;
  const int wave = tid >> 6;
  const int wr = wave >> 1, wc = wave & 1;
  int bx, by;
  xcd_tile(bx, by);
  const size_t rowA = (size_t)bx * 256;
  const size_t rowB = (size_t)by * 256;
  const int8_t* gA = Aq + rowA * K;
  const int8_t* gB = Bq + rowB * K;

  v16i acc[2][4];
#pragma unroll
  for (int a = 0; a < 2; ++a)
#pragma unroll
    for (int b = 0; b < 4; ++b)
#pragma unroll
      for (int r = 0; r < 16; ++r) acc[a][b][r] = 0;

  const int nt = K / BK;
  stage_rows512<4>(gA, K, 0, lsA[0], tid);
  stage_rows512<4>(gB, K, 0, lsB[0], tid);
  asm volatile("s_waitcnt vmcnt(0)" ::: "memory");
  __builtin_amdgcn_s_barrier();

  for (int t = 0; t < nt; ++t) {
    const int p = t & 1;
    if (t + 1 < nt) {
      const int kt = (t + 1) * BK;
      stage_rows512<4>(gA, K, kt, lsA[p ^ 1], tid);
      stage_rows512<4>(gB, K, kt, lsB[p ^ 1], tid);
    }
#pragma unroll
    for (int kk = 0; kk < 4; ++kk) {
      v4i a0 = read_frag(lsA[p], wr * 64, kk, lane);
      v4i a1 = read_frag(lsA[p], wr * 64 + 32, kk, lane);
      v4i b0 = read_frag(lsB[p], wc * 128, kk, lane);
      v4i b1 = read_frag(lsB[p], wc * 128 + 32, kk, lane);
      v4i b2 = read_frag(lsB[p], wc * 128 + 64, kk, lane);
      v4i b3 = read_frag(lsB[p], wc * 128 + 96, kk, lane);
      __builtin_amdgcn_s_barrier();
      __builtin_amdgcn_s_setprio(1);
      acc[0][0] = __builtin_amdgcn_mfma_i32_32x32x32_i8(a0, b0, acc[0][0], 0, 0, 0);
      acc[1][0] = __builtin_amdgcn_mfma_i32_32x32x32_i8(a1, b0, acc[1][0], 0, 0, 0);
      acc[0][1] = __builtin_amdgcn_mfma_i32_32x32x32_i8(a0, b1, acc[0][1], 0, 0, 0);
      acc[1][1] = __builtin_amdgcn_mfma_i32_32x32x32_i8(a1, b1, acc[1][1], 0, 0, 0);
      acc[0][2] = __builtin_amdgcn_mfma_i32_32x32x32_i8(a0, b2, acc[0][2], 0, 0, 0);
      acc[1][2] = __builtin_amdgcn_mfma_i32_32x32x32_i8(a1, b2, acc[1][2], 0, 0, 0);
      acc[0][3] = __builtin_amdgcn_mfma_i32_32x32x32_i8(a0, b3, acc[0][3], 0, 0, 0);
      acc[1][3] = __builtin_amdgcn_mfma_i32_32x32x32_i8(a1, b3, acc[1][3], 0, 0, 0);
      __builtin_amdgcn_s_setprio(0);
      if (kk == 3) asm volatile("s_waitcnt vmcnt(0)" ::: "memory");
      __builtin_amdgcn_s_barrier();
    }
  }

#pragma unroll
  for (int mi = 0; mi < 2; ++mi)
#pragma unroll
    for (int ni = 0; ni < 4; ++ni) {
#pragma unroll
      for (int r = 0; r < 16; ++r) {
        int rl = wr * 64 + mi * 32 + (r & 3) + 8 * (r >> 2) + 4 * (lane >> 5);
        int cl = wc * 128 + ni * 32 + (lane & 31);
        size_t m = rowA + rl, n = rowB + cl;
        C[m * (size_t)N + n] = (float)acc[mi][ni][r] * sa[m] * sb[n];
      }
    }
}

extern "C" void kernel_launch(void* const* d_in, const int* in_sizes, int n_in,
                              void* d_out, int out_size, void* d_ws, size_t ws_size,
                              hipStream_t stream) {
  const int T = 4096, HID = 4096, INTER = 11008;
  const float* x  = (const float*)d_in[0];
  const float* wg = (const float*)d_in[1];
  const float* wu = (const float*)d_in[2];
  const float* wd = (const float*)d_in[3];
  float* out = (float*)d_out;

  char* base = (char*)d_ws;
  size_t off = 0;
  auto alloc = [&](size_t b) {
    void* p = base + off;
    off += (b + 255) & ~(size_t)255;
    return p;
  };
  int8_t* xq  = (int8_t*)alloc((size_t)T * HID);
  float*  sx  = (float*)alloc((size_t)T * 4);
  int8_t* wgq = (int8_t*)alloc((size_t)INTER * HID);
  float*  sg  = (float*)alloc((size_t)INTER * 4);
  int8_t* wuq = (int8_t*)alloc((size_t)INTER * HID);
  float*  su  = (float*)alloc((size_t)INTER * 4);
  int8_t* wdq = (int8_t*)alloc((size_t)HID * INTER);
  float*  sd  = (float*)alloc((size_t)HID * 4);
  const size_t fixed = off;

  // choose largest token-chunk whose h/hq buffers fit in ws (multiple of 256)
  auto need = [&](int ch) {
    size_t n = fixed;
    n += (((size_t)ch * INTER) + 255) & ~(size_t)255;      // hq
    n += (((size_t)ch * 4) + 255) & ~(size_t)255;          // sh
    n += (((size_t)ch * INTER * 4) + 255) & ~(size_t)255;  // h
    return n;
  };
  int CH = 4096;
  while (CH > 256 && need(CH) > ws_size) CH >>= 1;
  int8_t* hq = (int8_t*)alloc((size_t)CH * INTER);
  float*  sh = (float*)alloc((size_t)CH * 4);
  float*  h  = (float*)alloc((size_t)CH * INTER * 4);

  // quantize activations and weights (single HBM pass, exact int8 per-row)
  quant_rows<4><<<T, 256, 0, stream>>>(x, HID, xq, sx);
  quant_rows<4><<<INTER, 256, 0, stream>>>(wg, HID, wgq, sg);
  quant_rows<4><<<INTER, 256, 0, stream>>>(wu, HID, wuq, su);
  quant_rows<11><<<HID, 256, 0, stream>>>(wd, INTER, wdq, sd);

  for (int c = 0; c < T; c += CH) {
    dim3 g1(CH / 256, INTER / 128);
    gemm_gateup<<<g1, 512, 0, stream>>>(xq + (size_t)c * HID, sx + c,
                                        wgq, sg, wuq, su, h, CH, INTER, HID);
    quant_rows<11><<<CH, 256, 0, stream>>>(h, INTER, hq, sh);
    dim3 g2(CH / 256, HID / 256);
    gemm_down<<<g2, 512, 0, stream>>>(hq, sh, wdq, sd, out + (size_t)c * HID,
                                      CH, HID, INTER);
  }
}

// Round 2
// 1271.735 us; speedup vs baseline: 1.1057x; 1.1057x over previous
//
#include <hip/hip_runtime.h>
#include <cstdint>
#include <cstddef>

typedef int v4i __attribute__((ext_vector_type(4)));
typedef int v16i __attribute__((ext_vector_type(16)));

#define BK 128    // bytes of K per LDS tile (i8)
#define HKB 64    // bytes of K per half-tile
#define AH 16384  // half stride, 256-row operand (256*64)
#define WH 8192   // half stride, 128-row operand (128*64)

// ---------------- async global->LDS, 16B per lane ----------------
__device__ __forceinline__ void gld_lds16(const void* g, void* l) {
  __builtin_amdgcn_global_load_lds(
      (const __attribute__((address_space(1))) unsigned int*)g,
      (__attribute__((address_space(3))) unsigned int*)l, 16, 0, 0);
}

// Stage one K-half (64 B per row, NI*128 rows) into a contiguous LDS
// half-buffer. LDS slot (r, c) holds global chunk c ^ (r&3). Dest is linear
// (slot f -> offset f*16) per the global_load_lds contract; the swizzle rides
// on the per-lane global source address.
template <int NI>
__device__ __forceinline__ void stage_half(const int8_t* __restrict__ g0, int K,
                                           int koff, int8_t* lds, int tid) {
#pragma unroll
  for (int i = 0; i < NI; ++i) {
    const int f = i * 512 + tid;
    const int r = f >> 2;
    const int cg = (f & 3) ^ (r & 3);
    gld_lds16(g0 + (size_t)r * K + koff + cg * 16, lds + (f & ~63) * 16);
  }
}

// Read one 32x32x32 i8 operand fragment (16 B). Operand contract (verified):
// row = lane&31, global k-chunk = kk*2 + (lane>>5). Half-major LDS: half
// = kk>>1, in-half chunk c = chunk&3, stored at slot c^(r&3). 8 consecutive
// lanes hit 4 bank-quads x2 => 2-way aliasing (free per m136).
__device__ __forceinline__ v4i read_frag2(const int8_t* lds, int HB, int row0,
                                          int kk, int lane) {
  const int r = row0 + (lane & 31);
  const int c = (kk * 2 + (lane >> 5)) & 3;
  return *(const v4i*)(lds + (kk >> 1) * HB + r * 64 + ((c ^ (r & 3)) << 4));
}

// XCD-contiguous tile remap (bijective iff nwg%8==0, else identity).
__device__ __forceinline__ void xcd_tile(int& bx, int& by) {
  const int gx = gridDim.x;
  const int nwg = gx * gridDim.y;
  int t = blockIdx.x + blockIdx.y * gx;
  if ((nwg & 7) == 0) t = (t & 7) * (nwg >> 3) + (t >> 3);
  bx = t % gx;
  by = t / gx;
}

// ---------------- per-row symmetric int8 quantization (single HBM pass) ----
template <int MAXIT>
__global__ __launch_bounds__(256) void quant_rows(const float* __restrict__ X, int C,
                                                  int8_t* __restrict__ Q,
                                                  float* __restrict__ S) {
  const int row = blockIdx.x;
  const float* x = X + (size_t)row * C;
  const int tid = threadIdx.x;
  float4 buf[MAXIT];
  float mx = 0.f;
#pragma unroll
  for (int it = 0; it < MAXIT; ++it) {
    int i = tid * 4 + it * 1024;
    if (i < C) {
      const float4 v = *(const float4*)(x + i);
      buf[it] = v;
      mx = fmaxf(mx, fmaxf(fmaxf(fabsf(v.x), fabsf(v.y)), fmaxf(fabsf(v.z), fabsf(v.w))));
    }
  }
#pragma unroll
  for (int off = 32; off; off >>= 1) mx = fmaxf(mx, __shfl_xor(mx, off));
  __shared__ float wmx[4];
  if ((tid & 63) == 0) wmx[tid >> 6] = mx;
  __syncthreads();
  mx = fmaxf(fmaxf(wmx[0], wmx[1]), fmaxf(wmx[2], wmx[3]));
  const float s = fmaxf(mx / 127.0f, 1e-8f);
  if (tid == 0) S[row] = s;
  int8_t* q = Q + (size_t)row * C;
#pragma unroll
  for (int it = 0; it < MAXIT; ++it) {
    int i = tid * 4 + it * 1024;
    if (i < C) {
      const float4 v = buf[it];
      int q0 = (int)fminf(fmaxf(rintf(v.x / s), -128.f), 127.f);
      int q1 = (int)fminf(fmaxf(rintf(v.y / s), -128.f), 127.f);
      int q2 = (int)fminf(fmaxf(rintf(v.z / s), -128.f), 127.f);
      int q3 = (int)fminf(fmaxf(rintf(v.w / s), -128.f), 127.f);
      *(int*)(q + i) = (q0 & 255) | ((q1 & 255) << 8) | ((q2 & 255) << 16) | ((q3 & 255) << 24);
    }
  }
}

#define WAIT4 asm volatile("s_waitcnt vmcnt(4)" ::: "memory")
#define WAIT0 asm volatile("s_waitcnt vmcnt(0)" ::: "memory")
// In steady state 8 loads are in flight (2 per phase); vmcnt(4) retires the
// oldest 4 = exactly the half the next phase pair needs. Last tile: drain.
#define WAITC do { if (stg) WAIT4; else WAIT0; } while (0)

// ---------------- fused gate+up int8 GEMM, SwiGLU epilogue -> h fp32 --------
// 256x128 tile, 8 waves (4M x 2N). 4 phases/K-tile; each phase: 6 ds_read,
// 2 prefetch loads, barrier, 8 MFMA under setprio, counted vmcnt (T3+T4+T5).
#define GU_PHASE(kk, STAGE_STMT, WAIT_STMT)                                          \
  {                                                                                  \
    v4i a0 = read_frag2(Ap, AH, wr * 64, kk, lane);                                  \
    v4i a1 = read_frag2(Ap, AH, wr * 64 + 32, kk, lane);                             \
    v4i bg0 = read_frag2(Gp, WH, wc * 64, kk, lane);                                 \
    v4i bu0 = read_frag2(Up, WH, wc * 64, kk, lane);                                 \
    v4i bg1 = read_frag2(Gp, WH, wc * 64 + 32, kk, lane);                            \
    v4i bu1 = read_frag2(Up, WH, wc * 64 + 32, kk, lane);                            \
    STAGE_STMT;                                                                      \
    __builtin_amdgcn_s_barrier();                                                    \
    __builtin_amdgcn_s_setprio(1);                                                   \
    accg[0][0] = __builtin_amdgcn_mfma_i32_32x32x32_i8(a0, bg0, accg[0][0], 0, 0, 0);\
    accg[1][0] = __builtin_amdgcn_mfma_i32_32x32x32_i8(a1, bg0, accg[1][0], 0, 0, 0);\
    accu[0][0] = __builtin_amdgcn_mfma_i32_32x32x32_i8(a0, bu0, accu[0][0], 0, 0, 0);\
    accu[1][0] = __builtin_amdgcn_mfma_i32_32x32x32_i8(a1, bu0, accu[1][0], 0, 0, 0);\
    accg[0][1] = __builtin_amdgcn_mfma_i32_32x32x32_i8(a0, bg1, accg[0][1], 0, 0, 0);\
    accg[1][1] = __builtin_amdgcn_mfma_i32_32x32x32_i8(a1, bg1, accg[1][1], 0, 0, 0);\
    accu[0][1] = __builtin_amdgcn_mfma_i32_32x32x32_i8(a0, bu1, accu[0][1], 0, 0, 0);\
    accu[1][1] = __builtin_amdgcn_mfma_i32_32x32x32_i8(a1, bu1, accu[1][1], 0, 0, 0);\
    __builtin_amdgcn_s_setprio(0);                                                   \
    WAIT_STMT;                                                                       \
    __builtin_amdgcn_s_barrier();                                                    \
  }

__global__ __launch_bounds__(512, 2) void gemm_gateup(
    const int8_t* __restrict__ Xq, const float* __restrict__ sx,
    const int8_t* __restrict__ Wg, const float* __restrict__ sg,
    const int8_t* __restrict__ Wu, const float* __restrict__ su,
    float* __restrict__ H, int M, int N, int K) {
  __shared__ __align__(16) int8_t lsA[2][256 * BK];
  __shared__ __align__(16) int8_t lsG[2][128 * BK];
  __shared__ __align__(16) int8_t lsU[2][128 * BK];
  const int tid = threadIdx.x;
  const int lane = tid & 63;
  const int wave = tid >> 6;
  const int wr = wave >> 1, wc = wave & 1;
  int bx, by;
  xcd_tile(bx, by);
  const size_t rowA = (size_t)bx * 256;
  const size_t rowB = (size_t)by * 128;
  const int8_t* gA = Xq + rowA * K;
  const int8_t* gG = Wg + rowB * K;
  const int8_t* gU = Wu + rowB * K;

  v16i accg[2][2], accu[2][2];
#pragma unroll
  for (int a = 0; a < 2; ++a)
#pragma unroll
    for (int b = 0; b < 2; ++b)
#pragma unroll
      for (int r = 0; r < 16; ++r) { accg[a][b][r] = 0; accu[a][b][r] = 0; }

  const int nt = K / BK;
  // prologue: tile 0 both halves (h0 first), ensure h0 resident (vmcnt(4))
  stage_half<2>(gA, K, 0, lsA[0], tid);
  stage_half<1>(gG, K, 0, lsG[0], tid);
  stage_half<1>(gU, K, 0, lsU[0], tid);
  stage_half<2>(gA, K, HKB, lsA[0] + AH, tid);
  stage_half<1>(gG, K, HKB, lsG[0] + WH, tid);
  stage_half<1>(gU, K, HKB, lsU[0] + WH, tid);
  WAIT4;
  __builtin_amdgcn_s_barrier();

  for (int t = 0; t < nt; ++t) {
    const int p = t & 1;
    const bool stg = (t + 1 < nt);
    const int ktN = (t + 1) * BK;
    const int8_t* Ap = lsA[p];
    const int8_t* Gp = lsG[p];
    const int8_t* Up = lsU[p];
    int8_t* An = lsA[p ^ 1];
    int8_t* Gn = lsG[p ^ 1];
    int8_t* Un = lsU[p ^ 1];

    GU_PHASE(0, if (stg) stage_half<2>(gA, K, ktN, An, tid), (void)0);
    GU_PHASE(1, if (stg) { stage_half<1>(gG, K, ktN, Gn, tid);
                           stage_half<1>(gU, K, ktN, Un, tid); }, WAITC);
    GU_PHASE(2, if (stg) stage_half<2>(gA, K, ktN + HKB, An + AH, tid), (void)0);
    GU_PHASE(3, if (stg) { stage_half<1>(gG, K, ktN + HKB, Gn + WH, tid);
                           stage_half<1>(gU, K, ktN + HKB, Un + WH, tid); }, WAITC);
  }

#pragma unroll
  for (int mi = 0; mi < 2; ++mi)
#pragma unroll
    for (int ni = 0; ni < 2; ++ni) {
#pragma unroll
      for (int r = 0; r < 16; ++r) {
        int rl = wr * 64 + mi * 32 + (r & 3) + 8 * (r >> 2) + 4 * (lane >> 5);
        int cl = wc * 64 + ni * 32 + (lane & 31);
        size_t m = rowA + rl, n = rowB + cl;
        float sxm = sx[m];
        float g = (float)accg[mi][ni][r] * sxm * sg[n];
        float u = (float)accu[mi][ni][r] * sxm * su[n];
        float hv = g / (1.0f + __expf(-g)) * u;  // silu(g)*u
        H[m * (size_t)N + n] = hv;
      }
    }
}

// ---------------- int8 GEMM, scale epilogue -> fp32 out ---------------------
// 256x256 tile, 8 waves (4M x 2N), wave-tile 64x128. Same pipeline schedule.
#define DN_PHASE(kk, STAGE_STMT, WAIT_STMT)                                          \
  {                                                                                  \
    v4i a0 = read_frag2(Ap, AH, wr * 64, kk, lane);                                  \
    v4i a1 = read_frag2(Ap, AH, wr * 64 + 32, kk, lane);                             \
    v4i b0 = read_frag2(Bp, AH, wc * 128, kk, lane);                                 \
    v4i b1 = read_frag2(Bp, AH, wc * 128 + 32, kk, lane);                            \
    v4i b2 = read_frag2(Bp, AH, wc * 128 + 64, kk, lane);                            \
    v4i b3 = read_frag2(Bp, AH, wc * 128 + 96, kk, lane);                            \
    STAGE_STMT;                                                                      \
    __builtin_amdgcn_s_barrier();                                                    \
    __builtin_amdgcn_s_setprio(1);                                                   \
    acc[0][0] = __builtin_amdgcn_mfma_i32_32x32x32_i8(a0, b0, acc[0][0], 0, 0, 0);   \
    acc[1][0] = __builtin_amdgcn_mfma_i32_32x32x32_i8(a1, b0, acc[1][0], 0, 0, 0);   \
    acc[0][1] = __builtin_amdgcn_mfma_i32_32x32x32_i8(a0, b1, acc[0][1], 0, 0, 0);   \
    acc[1][1] = __builtin_amdgcn_mfma_i32_32x32x32_i8(a1, b1, acc[1][1], 0, 0, 0);   \
    acc[0][2] = __builtin_amdgcn_mfma_i32_32x32x32_i8(a0, b2, acc[0][2], 0, 0, 0);   \
    acc[1][2] = __builtin_amdgcn_mfma_i32_32x32x32_i8(a1, b2, acc[1][2], 0, 0, 0);   \
    acc[0][3] = __builtin_amdgcn_mfma_i32_32x32x32_i8(a0, b3, acc[0][3], 0, 0, 0);   \
    acc[1][3] = __builtin_amdgcn_mfma_i32_32x32x32_i8(a1, b3, acc[1][3], 0, 0, 0);   \
    __builtin_amdgcn_s_setprio(0);                                                   \
    WAIT_STMT;                                                                       \
    __builtin_amdgcn_s_barrier();                                                    \
  }

__global__ __launch_bounds__(512, 2) void gemm_down(
    const int8_t* __restrict__ Aq, const float* __restrict__ sa,
    const int8_t* __restrict__ Bq, const float* __restrict__ sb,
    float* __restrict__ C, int M, int N, int K) {
  __shared__ __align__(16) int8_t lsA[2][256 * BK];
  __shared__ __align__(16) int8_t lsB[2][256 * BK];
  const int tid = threadIdx.x;
  const int lane = tid & 63;
  const int wave = tid >> 6;
  const int wr = wave >> 1, wc = wave & 1;
  int bx, by;
  xcd_tile(bx, by);
  const size_t rowA = (size_t)bx * 256;
  const size_t rowB = (size_t)by * 256;
  const int8_t* gA = Aq + rowA * K;
  const int8_t* gB = Bq + rowB * K;

  v16i acc[2][4];
#pragma unroll
  for (int a = 0; a < 2; ++a)
#pragma unroll
    for (int b = 0; b < 4; ++b)
#pragma unroll
      for (int r = 0; r < 16; ++r) acc[a][b][r] = 0;

  const int nt = K / BK;
  stage_half<2>(gA, K, 0, lsA[0], tid);
  stage_half<2>(gB, K, 0, lsB[0], tid);
  stage_half<2>(gA, K, HKB, lsA[0] + AH, tid);
  stage_half<2>(gB, K, HKB, lsB[0] + AH, tid);
  WAIT4;
  __builtin_amdgcn_s_barrier();

  for (int t = 0; t < nt; ++t) {
    const int p = t & 1;
    const bool stg = (t + 1 < nt);
    const int ktN = (t + 1) * BK;
    const int8_t* Ap = lsA[p];
    const int8_t* Bp = lsB[p];
    int8_t* An = lsA[p ^ 1];
    int8_t* Bn = lsB[p ^ 1];

    DN_PHASE(0, if (stg) stage_half<2>(gA, K, ktN, An, tid), (void)0);
    DN_PHASE(1, if (stg) stage_half<2>(gB, K, ktN, Bn, tid), WAITC);
    DN_PHASE(2, if (stg) stage_half<2>(gA, K, ktN + HKB, An + AH, tid), (void)0);
    DN_PHASE(3, if (stg) stage_half<2>(gB, K, ktN + HKB, Bn + AH, tid), WAITC);
  }

#pragma unroll
  for (int mi = 0; mi < 2; ++mi)
#pragma unroll
    for (int ni = 0; ni < 4; ++ni) {
#pragma unroll
      for (int r = 0; r < 16; ++r) {
        int rl = wr * 64 + mi * 32 + (r & 3) + 8 * (r >> 2) + 4 * (lane >> 5);
        int cl = wc * 128 + ni * 32 + (lane & 31);
        size_t m = rowA + rl, n = rowB + cl;
        C[m * (size_t)N + n] = (float)acc[mi][ni][r] * sa[m] * sb[n];
      }
    }
}

extern "C" void kernel_launch(void* const* d_in, const int* in_sizes, int n_in,
                              void* d_out, int out_size, void* d_ws, size_t ws_size,
                              hipStream_t stream) {
  const int T = 4096, HID = 4096, INTER = 11008;
  const float* x  = (const float*)d_in[0];
  const float* wg = (const float*)d_in[1];
  const float* wu = (const float*)d_in[2];
  const float* wd = (const float*)d_in[3];
  float* out = (float*)d_out;

  char* base = (char*)d_ws;
  size_t off = 0;
  auto alloc = [&](size_t b) {
    void* p = base + off;
    off += (b + 255) & ~(size_t)255;
    return p;
  };
  int8_t* xq  = (int8_t*)alloc((size_t)T * HID);
  float*  sx  = (float*)alloc((size_t)T * 4);
  int8_t* wgq = (int8_t*)alloc((size_t)INTER * HID);
  float*  sg  = (float*)alloc((size_t)INTER * 4);
  int8_t* wuq = (int8_t*)alloc((size_t)INTER * HID);
  float*  su  = (float*)alloc((size_t)INTER * 4);
  int8_t* wdq = (int8_t*)alloc((size_t)HID * INTER);
  float*  sd  = (float*)alloc((size_t)HID * 4);
  const size_t fixed = off;

  // choose largest token-chunk whose h/hq buffers fit in ws (multiple of 256)
  auto need = [&](int ch) {
    size_t n = fixed;
    n += (((size_t)ch * INTER) + 255) & ~(size_t)255;      // hq
    n += (((size_t)ch * 4) + 255) & ~(size_t)255;          // sh
    n += (((size_t)ch * INTER * 4) + 255) & ~(size_t)255;  // h
    return n;
  };
  int CH = 4096;
  while (CH > 256 && need(CH) > ws_size) CH >>= 1;
  int8_t* hq = (int8_t*)alloc((size_t)CH * INTER);
  float*  sh = (float*)alloc((size_t)CH * 4);
  float*  h  = (float*)alloc((size_t)CH * INTER * 4);

  // quantize activations and weights (single HBM pass, exact int8 per-row)
  quant_rows<4><<<T, 256, 0, stream>>>(x, HID, xq, sx);
  quant_rows<4><<<INTER, 256, 0, stream>>>(wg, HID, wgq, sg);
  quant_rows<4><<<INTER, 256, 0, stream>>>(wu, HID, wuq, su);
  quant_rows<11><<<HID, 256, 0, stream>>>(wd, INTER, wdq, sd);

  for (int c = 0; c < T; c += CH) {
    dim3 g1(CH / 256, INTER / 128);
    gemm_gateup<<<g1, 512, 0, stream>>>(xq + (size_t)c * HID, sx + c,
                                        wgq, sg, wuq, su, h, CH, INTER, HID);
    quant_rows<11><<<CH, 256, 0, stream>>>(h, INTER, hq, sh);
    dim3 g2(CH / 256, HID / 256);
    gemm_down<<<g2, 512, 0, stream>>>(hq, sh, wdq, sd, out + (size_t)c * HID,
                                      CH, HID, INTER);
  }
}